// Round 1
// baseline (188.883 us; speedup 1.0000x reference)
//
#include <hip/hip_runtime.h>
#include <hip/hip_bf16.h>

typedef __attribute__((ext_vector_type(8))) short bf16x8;
typedef __attribute__((ext_vector_type(4))) float f32x4;

#define BNSCL 0.9999950000375f   /* 1/sqrt(1+1e-5) */

// ---------------------------------------------------------------------------
// Kernel 0: rearrange weight_bank (128c,8m,64o) fp32 -> wbT bf16 [o][cm=c*8+m]
// ---------------------------------------------------------------------------
__global__ __launch_bounds__(256) void k_prep_wbt(const float* __restrict__ wb,
                                                  __hip_bfloat16* __restrict__ wbt)
{
    int idx = blockIdx.x * 256 + threadIdx.x;   // 0..65535
    int o = idx >> 10;
    int cm = idx & 1023;
    wbt[idx] = __float2bfloat16(wb[cm * 64 + o]);
}

// ---------------------------------------------------------------------------
// Kernel 1: per-point scores MLP + softmax -> scores[g*8 + m] fp32
// ---------------------------------------------------------------------------
__global__ __launch_bounds__(256) void k_scores(
    const float* __restrict__ xyz,
    const float* __restrict__ w1, const float* __restrict__ g1, const float* __restrict__ be1,
    const float* __restrict__ w2, const float* __restrict__ g2, const float* __restrict__ be2,
    const float* __restrict__ w3, const float* __restrict__ g3, const float* __restrict__ be3,
    const float* __restrict__ w4, const float* __restrict__ b4,
    float* __restrict__ scores)
{
    int g = blockIdx.x * 256 + threadIdx.x;     // 0..262143
    int b = g >> 15;
    int p = g & 32767;
    int pc = p & ~31;                            // k=0 neighbor (center)
    const float* xb = xyz + (size_t)b * 98304;   // (3, 32768)
    float cx = xb[pc], cy = xb[32768 + pc], cz = xb[65536 + pc];
    float dx = xb[p] - cx, dy = xb[32768 + p] - cy, dz = xb[65536 + p] - cz;
    float dist = sqrtf(dx * dx + dy * dy + dz * dz);
    float in7[7] = {cx, cy, cz, dx, dy, dz, dist};

    float h1[16], h2[16];
#pragma unroll
    for (int o = 0; o < 16; ++o) {
        float a = 0.f;
#pragma unroll
        for (int c = 0; c < 7; ++c) a += w1[o * 7 + c] * in7[c];
        h1[o] = fmaxf(a * (g1[o] * BNSCL) + be1[o], 0.f);
    }
#pragma unroll
    for (int o = 0; o < 16; ++o) {
        float a = 0.f;
#pragma unroll
        for (int c = 0; c < 16; ++c) a += w2[o * 16 + c] * h1[c];
        h2[o] = fmaxf(a * (g2[o] * BNSCL) + be2[o], 0.f);
    }
#pragma unroll
    for (int o = 0; o < 16; ++o) {
        float a = 0.f;
#pragma unroll
        for (int c = 0; c < 16; ++c) a += w3[o * 16 + c] * h2[c];
        h1[o] = fmaxf(a * (g3[o] * BNSCL) + be3[o], 0.f);   // reuse h1 = h3
    }
    float s[8];
#pragma unroll
    for (int o = 0; o < 8; ++o) {
        float a = b4[o];
#pragma unroll
        for (int c = 0; c < 16; ++c) a += w4[o * 16 + c] * h1[c];
        s[o] = a;
    }
    float mx = s[0];
#pragma unroll
    for (int i = 1; i < 8; ++i) mx = fmaxf(mx, s[i]);
    float sum = 0.f;
#pragma unroll
    for (int i = 0; i < 8; ++i) { s[i] = __expf(s[i] - mx); sum += s[i]; }
    float inv = 1.f / sum;
    float4 lo = {s[0] * inv, s[1] * inv, s[2] * inv, s[3] * inv};
    float4 hi = {s[4] * inv, s[5] * inv, s[6] * inv, s[7] * inv};
    *(float4*)(scores + (size_t)g * 8) = lo;
    *(float4*)(scores + (size_t)g * 8 + 4) = hi;
}

// ---------------------------------------------------------------------------
// Kernel 2: main einsum via MFMA.  D[o,p] = sum_cm wbT[o,cm] * (feat*s)[cm,p]
// Block = 512 thr (8 waves), 128 points. LDS = wbT half (64 o x 512 cm bf16,
// XOR-swizzled by 16B chunk) = 64 KB -> 2 blocks/CU.
// ---------------------------------------------------------------------------
__global__ __launch_bounds__(512, 4) void k_main(
    const float* __restrict__ feat,
    const float* __restrict__ scores,
    const __hip_bfloat16* __restrict__ wbt,
    const float* __restrict__ bn_g, const float* __restrict__ bn_b,
    float* __restrict__ out)
{
    __shared__ __align__(16) short lwb[64 * 512];

    const int tid  = threadIdx.x;
    const int lane = tid & 63;
    const int wave = tid >> 6;          // 0..7
    const int col  = lane & 15;         // p within tile / o within A-row tile
    const int row4 = lane >> 4;         // 0..3 (k-quad)

    const int pblock = blockIdx.x * 128;
    const int b    = pblock >> 15;
    const int pl0  = pblock & 32767;
    const int pcol = pl0 + wave * 16 + col;   // point within batch b
    const int pcen = pcol & ~31;              // wave-uniform center (k=0)
    const int gp   = pblock + wave * 16 + col;

    const float* fb = feat + (size_t)b * 2097152;   // (64, 32768)

    const float* sp = scores + (size_t)gp * 8;
    float4 sl = *(const float4*)sp;
    float4 sh = *(const float4*)(sp + 4);

    f32x4 acc[4];
#pragma unroll
    for (int i = 0; i < 4; ++i) { f32x4 z = {0.f, 0.f, 0.f, 0.f}; acc[i] = z; }

    const ushort* wsrc = (const ushort*)wbt;

    // ---------------- phase 0 : cm 0..511 (c' < 64 : f - f_center) -----------
#pragma unroll
    for (int it = 0; it < 8; ++it) {
        int chunk = it * 512 + tid;     // 0..4095
        int o = chunk >> 6, c8 = chunk & 63;
        int4 v = *(const int4*)(wsrc + (o << 10) + (c8 << 3));
        *(int4*)&lwb[(o << 9) + (((c8 ^ o) & 63) << 3)] = v;
    }
    __syncthreads();

#pragma unroll 4
    for (int kk = 0; kk < 16; ++kk) {
        int c = kk * 4 + row4;                       // c' = c  (diff half)
        const float* fpc = fb + (size_t)c * 32768;
        float fv = fpc[pcol] - fpc[pcen];

        int4 bi;
        { __hip_bfloat162 q = __float22bfloat162_rn(make_float2(fv * sl.x, fv * sl.y)); __builtin_memcpy(&bi.x, &q, 4); }
        { __hip_bfloat162 q = __float22bfloat162_rn(make_float2(fv * sl.z, fv * sl.w)); __builtin_memcpy(&bi.y, &q, 4); }
        { __hip_bfloat162 q = __float22bfloat162_rn(make_float2(fv * sh.x, fv * sh.y)); __builtin_memcpy(&bi.z, &q, 4); }
        { __hip_bfloat162 q = __float22bfloat162_rn(make_float2(fv * sh.z, fv * sh.w)); __builtin_memcpy(&bi.w, &q, 4); }
        bf16x8 bv = __builtin_bit_cast(bf16x8, bi);

        int bcm = kk * 4 + row4;
#pragma unroll
        for (int ot = 0; ot < 4; ++ot) {
            int o = ot * 16 + col;
            bf16x8 af = *(const bf16x8*)&lwb[(o << 9) + (((bcm ^ o) & 63) << 3)];
            acc[ot] = __builtin_amdgcn_mfma_f32_16x16x32_bf16(af, bv, acc[ot], 0, 0, 0);
        }
    }
    __syncthreads();

    // ---------------- phase 1 : cm 512..1023 (c' >= 64 : raw f) --------------
#pragma unroll
    for (int it = 0; it < 8; ++it) {
        int chunk = it * 512 + tid;
        int o = chunk >> 6, c8 = chunk & 63;
        int4 v = *(const int4*)(wsrc + (o << 10) + 512 + (c8 << 3));
        *(int4*)&lwb[(o << 9) + (((c8 ^ o) & 63) << 3)] = v;
    }
    __syncthreads();

#pragma unroll 4
    for (int kk = 0; kk < 16; ++kk) {
        int c = kk * 4 + row4;                       // c' = 64 + c  (raw half)
        float fv = fb[(size_t)c * 32768 + pcol];

        int4 bi;
        { __hip_bfloat162 q = __float22bfloat162_rn(make_float2(fv * sl.x, fv * sl.y)); __builtin_memcpy(&bi.x, &q, 4); }
        { __hip_bfloat162 q = __float22bfloat162_rn(make_float2(fv * sl.z, fv * sl.w)); __builtin_memcpy(&bi.y, &q, 4); }
        { __hip_bfloat162 q = __float22bfloat162_rn(make_float2(fv * sh.x, fv * sh.y)); __builtin_memcpy(&bi.z, &q, 4); }
        { __hip_bfloat162 q = __float22bfloat162_rn(make_float2(fv * sh.z, fv * sh.w)); __builtin_memcpy(&bi.w, &q, 4); }
        bf16x8 bv = __builtin_bit_cast(bf16x8, bi);

        int bcm = kk * 4 + row4;
#pragma unroll
        for (int ot = 0; ot < 4; ++ot) {
            int o = ot * 16 + col;
            bf16x8 af = *(const bf16x8*)&lwb[(o << 9) + (((bcm ^ o) & 63) << 3)];
            acc[ot] = __builtin_amdgcn_mfma_f32_16x16x32_bf16(af, bv, acc[ot], 0, 0, 0);
        }
    }

    // ---------------- epilogue: BN + ReLU + coalesced store ------------------
#pragma unroll
    for (int ot = 0; ot < 4; ++ot) {
#pragma unroll
        for (int r = 0; r < 4; ++r) {
            int o = ot * 16 + row4 * 4 + r;          // D row = (lane>>4)*4 + reg
            float v = acc[ot][r];
            v = v * (bn_g[o] * BNSCL) + bn_b[o];
            v = fmaxf(v, 0.f);
            out[((size_t)(b * 64 + o) << 15) + pcol] = v;
        }
    }
}

// ---------------------------------------------------------------------------
extern "C" void kernel_launch(void* const* d_in, const int* in_sizes, int n_in,
                              void* d_out, int out_size, void* d_ws, size_t ws_size,
                              hipStream_t stream)
{
    const float* features = (const float*)d_in[0];
    const float* xyz      = (const float*)d_in[1];
    const float* w1  = (const float*)d_in[2];
    const float* g1  = (const float*)d_in[3];
    const float* be1 = (const float*)d_in[4];
    const float* w2  = (const float*)d_in[5];
    const float* g2  = (const float*)d_in[6];
    const float* be2 = (const float*)d_in[7];
    const float* w3  = (const float*)d_in[8];
    const float* g3  = (const float*)d_in[9];
    const float* be3 = (const float*)d_in[10];
    const float* w4  = (const float*)d_in[11];
    const float* b4  = (const float*)d_in[12];
    const float* wb  = (const float*)d_in[13];
    const float* bn_g = (const float*)d_in[14];
    const float* bn_b = (const float*)d_in[15];

    float* scores = (float*)d_ws;                                   // 8 MB
    __hip_bfloat16* wbt = (__hip_bfloat16*)((char*)d_ws + 8388608); // 128 KB

    k_prep_wbt<<<256, 256, 0, stream>>>(wb, wbt);
    k_scores<<<1024, 256, 0, stream>>>(xyz, w1, g1, be1, w2, g2, be2,
                                       w3, g3, be3, w4, b4, scores);
    k_main<<<2048, 512, 0, stream>>>(features, scores, wbt, bn_g, bn_b,
                                     (float*)d_out);
}